// Round 14
// baseline (117.044 us; speedup 1.0000x reference)
//
#include <hip/hip_runtime.h>
#include <hip/hip_bf16.h>
#include <math.h>

#define NB 8
#define NQ 256
#define NK 256
#define DIN 10
#define FDIM 64
#define HIDDEN 256
#define NH 8
#define ROWS_PER_BLK 4

#define FSTRIDE 64    // shorts per feat row; XOR-swizzled 8-short col-blocks
#define HSTRIDE 264   // shorts per h row (256 + 8 pad) -> 528 B

typedef float f32x4 __attribute__((ext_vector_type(4)));
typedef short bf16x8 __attribute__((ext_vector_type(8)));

// fast float->bf16 for setup paths (2 instrs, ties-away)
__device__ __forceinline__ short f2bf(float f) {
    return (short)((__float_as_uint(f) + 0x8000u) >> 16);
}
// hot-path pack: HW v_cvt_pk_bf16_f32 (1 instr, RNE) via HIP header;
// reinterpret via memcpy (bit_cast rejects non-trivially-copyable bf162)
__device__ __forceinline__ unsigned pk2(float a, float b) {
    __hip_bfloat162 h = __float22bfloat162_rn(make_float2(a, b));
    unsigned u;
    __builtin_memcpy(&u, &h, sizeof(u));
    return u;
}

__device__ __forceinline__ void four4(float x, float* dst) {
    float s1 = __sinf(x), c1 = __cosf(x);
    float s2 = 2.f * s1 * c1, c2 = 1.f - 2.f * s1 * s1;
    float s4 = 2.f * s2 * c2, c4 = 1.f - 2.f * s2 * s2;
    float s8 = 2.f * s4 * c4, c8 = 1.f - 2.f * s4 * s4;
    dst[0] = s1; dst[1] = s2; dst[2] = s4; dst[3] = s8;
    dst[4] = c1; dst[5] = c2; dst[6] = c4; dst[7] = c8;
}
__device__ __forceinline__ void four2(float x, float* dst) {
    float s1 = __sinf(x), c1 = __cosf(x);
    dst[0] = s1; dst[1] = 2.f * s1 * c1;
    dst[2] = c1; dst[3] = 1.f - 2.f * s1 * s1;
}

// r10 structure (best: 56.5 us) + w2-in-regs (r12-proven) + HW packed bf16
// converts. Block = (b, i0..i0+3), 4 waves; grid = 512 = 2 blocks/CU, one
// dispatch round. Per row: 4 chunks of 64 pairs; GEMM1' transposed
// (D[h][p], A = W1^T regs, B = feat^T LDS), silu -> h_s, all-wave GEMM2
// (A = h pair-major, B = w2f regs). Scale folds: W1,b1 x -log2e; W2 x -ln2.
// LDS 66560 B -> 2 blocks/CU.
__global__ __launch_bounds__(256, 2) void relfeat_mfma_kernel(
    const float* __restrict__ q, const float* __restrict__ k,
    const float* __restrict__ W1, const float* __restrict__ b1,
    const float* __restrict__ W2, const float* __restrict__ b2,
    float* __restrict__ out)
{
    __shared__ __align__(16) short feat_s[NK * FSTRIDE];   // 32768 B
    __shared__ __align__(16) short h_s[64 * HSTRIDE];      // 33792 B

    const int t = threadIdx.x;
    const int wave = t >> 6;
    const int l15 = t & 15;
    const int quad = (t >> 4) & 3;
    const int b = blockIdx.x >> 6;
    const int i0 = (blockIdx.x & 63) * ROWS_PER_BLK;
    const int swr = l15 & 7;

    // ---- k-row for pair j = t (block-invariant) ----
    const float* kp = k + ((size_t)b * NK + t) * DIN;
    const float k0 = kp[0], k3 = kp[3], k4 = kp[4], k5 = kp[5], k6 = kp[6],
                k7 = kp[7], k8 = kp[8];

    // ---- W2 B-fragments in regs, -ln2 scaled (r12-proven; lanes 8..15 dup) ----
    bf16x8 w2f[8];
#pragma unroll
    for (int k2 = 0; k2 < 8; ++k2) {
        bf16x8 v;
#pragma unroll
        for (int e = 0; e < 8; ++e)
            v[e] = f2bf(-0.69314718f *
                        W2[(size_t)(k2 * 32 + quad * 8 + e) * NH + (l15 & 7)]);
        w2f[k2] = v;
    }
    const float b2v = (l15 < NH) ? b2[l15] : 0.f;

    // ---- W1 fragments (A operand), -log2e scaled (r10-proven) ----
    const int n0 = wave * 64;
    bf16x8 w1f[4][2];
#pragma unroll
    for (int nt = 0; nt < 4; ++nt)
#pragma unroll
        for (int ks = 0; ks < 2; ++ks) {
            const float* wp = W1 + (size_t)(ks * 32 + quad * 8) * HIDDEN
                              + (n0 + nt * 16 + l15);
            bf16x8 v;
#pragma unroll
            for (int e = 0; e < 8; ++e)
                v[e] = f2bf(-1.44269504f * wp[(size_t)e * HIDDEN]);
            w1f[nt][ks] = v;
        }
    float4 b1q[4];
#pragma unroll
    for (int nt = 0; nt < 4; ++nt) {
        float4 bb = *(const float4*)&b1[n0 + nt * 16 + quad * 4];
        b1q[nt] = make_float4(-1.44269504f * bb.x, -1.44269504f * bb.y,
                              -1.44269504f * bb.z, -1.44269504f * bb.w);
    }

    // ================= row loop =================
#pragma unroll 1
    for (int row = 0; row < ROWS_PER_BLK; ++row) {
        const int i = i0 + row;

        // ---- features for pair j = t (r5-proven math, r7-proven swizzle) ----
        {
            const float* qp = q + ((size_t)b * NQ + i) * DIN;
            const float q0 = qp[0], q3 = qp[3], q4 = qp[4], q5 = qp[5],
                        q6 = qp[6], q7 = qp[7], q8 = qp[8];

            const float dpx = k3 - q3, dpy = k4 - q4;
            const float dvx = k5 - q5, dvy = k6 - q6;
            const float dist = sqrtf(dpx * dpx + dpy * dpy + 1e-6f);
            const float inv_dist = 1.0f / (dist + 0.1f);
            const float inv_d2 = 1.0f / (dist + 1e-6f);
            const float bear_x = dpx * inv_d2, bear_y = dpy * inv_d2;
            const float ata = bear_x * q7 + bear_y * q8;
            const float aspect = bear_x * k7 + bear_y * k8;
            const float dot_dp_dv = dpx * dvx + dpy * dvy;
            const float speed_sq = dvx * dvx + dvy * dvy;
            const float ttca = tanhf(fmaxf(0.f, -dot_dp_dv / (speed_sq + 1e-6f)));
            const float same_team = (q0 == k0) ? 1.f : 0.f;
            const float q_speed = sqrtf(q5 * q5 + q6 * q6);
            const float k_speed = sqrtf(k5 * k5 + k6 * k6);
            const float delta_speed = k_speed - q_speed;

            float feat[FDIM];
            four4(dist,        feat + 0);
            four4(inv_dist,    feat + 8);
            four4(ata,         feat + 16);
            four4(aspect,      feat + 24);
            four2(dpx,         feat + 32);
            four2(dpy,         feat + 36);
            four2(dvx,         feat + 40);
            four2(dvy,         feat + 44);
            four2(ttca,        feat + 48);
            four2(dist,        feat + 52);
            four2(same_team,   feat + 56);
            four2(delta_speed, feat + 60);

            const int sw = t & 7;
#pragma unroll
            for (int c8 = 0; c8 < 8; ++c8) {
                uint4 v;
                v.x = pk2(feat[c8 * 8 + 0], feat[c8 * 8 + 1]);
                v.y = pk2(feat[c8 * 8 + 2], feat[c8 * 8 + 3]);
                v.z = pk2(feat[c8 * 8 + 4], feat[c8 * 8 + 5]);
                v.w = pk2(feat[c8 * 8 + 6], feat[c8 * 8 + 7]);
                *(uint4*)&feat_s[t * FSTRIDE + ((c8 ^ sw) * 8)] = v;
            }
        }
        __syncthreads();  // feat_s(row) ready

        // ---- 4 chunks of 64 pairs ----
#pragma unroll 1
        for (int c = 0; c < 4; ++c) {
            const int p0 = c * 64;

            // GEMM1': acc[nt][mt] -> D[hidden=n0+nt*16+quad*4+r][pair=p0+mt*16+l15]
            f32x4 acc[4][4];
#pragma unroll
            for (int nt = 0; nt < 4; ++nt)
#pragma unroll
                for (int mt = 0; mt < 4; ++mt)
                    acc[nt][mt] = (f32x4){b1q[nt].x, b1q[nt].y, b1q[nt].z, b1q[nt].w};
#pragma unroll
            for (int ks = 0; ks < 2; ++ks)
#pragma unroll
                for (int mt = 0; mt < 4; ++mt) {
                    const int r2 = p0 + mt * 16 + l15;
                    const bf16x8 fb = *(const bf16x8*)
                        &feat_s[r2 * FSTRIDE + (((ks * 4 + quad) ^ swr) * 8)];
#pragma unroll
                    for (int nt = 0; nt < 4; ++nt)
                        acc[nt][mt] = __builtin_amdgcn_mfma_f32_16x16x32_bf16(
                            w1f[nt][ks], fb, acc[nt][mt], 0, 0, 0);
                }

            __syncthreads();  // h_s(prev) fully consumed before overwrite

            // silu (scale-folded) -> HW packed bf16 -> one ds_write_b64
#pragma unroll
            for (int nt = 0; nt < 4; ++nt)
#pragma unroll
                for (int mt = 0; mt < 4; ++mt) {
                    const int pair = mt * 16 + l15;
                    const int hbase = n0 + nt * 16 + quad * 4;
                    float s[4];
#pragma unroll
                    for (int r = 0; r < 4; ++r) {
                        const float a = acc[nt][mt][r];     // = -log2e * preact
                        const float e = __builtin_amdgcn_exp2f(a);
                        s[r] = a * __builtin_amdgcn_rcpf(1.f + e);
                    }
                    uint2 pk;
                    pk.x = pk2(s[0], s[1]);
                    pk.y = pk2(s[2], s[3]);
                    *(uint2*)&h_s[pair * HSTRIDE + hbase] = pk;
                }
            __syncthreads();  // h_s(c) ready

            // GEMM2: each wave one 16-pair M-tile; K=256; W2 frags in regs
            {
                const int pw = wave * 16;
                f32x4 acc2 = (f32x4){b2v, b2v, b2v, b2v};
#pragma unroll
                for (int k2 = 0; k2 < 8; ++k2) {
                    const bf16x8 ha = *(const bf16x8*)&h_s[(pw + l15) * HSTRIDE
                                                            + k2 * 32 + quad * 8];
                    acc2 = __builtin_amdgcn_mfma_f32_16x16x32_bf16(
                        ha, w2f[k2], acc2, 0, 0, 0);
                }
                if (l15 < NH) {
                    float* op = out + (((size_t)b * NH + l15) * NQ + i) * NK
                                + (p0 + pw + quad * 4);
                    *(float4*)op = make_float4(acc2[0], acc2[1], acc2[2], acc2[3]);
                }
            }
            // no end barrier: next chunk's GEMM1' touches only feat_s
        }
    }
}

extern "C" void kernel_launch(void* const* d_in, const int* in_sizes, int n_in,
                              void* d_out, int out_size, void* d_ws, size_t ws_size,
                              hipStream_t stream) {
    const float* q  = (const float*)d_in[0];
    const float* k  = (const float*)d_in[1];
    const float* W1 = (const float*)d_in[2];
    const float* b1 = (const float*)d_in[3];
    const float* W2 = (const float*)d_in[4];
    const float* b2 = (const float*)d_in[5];
    float* out = (float*)d_out;

    dim3 grid(NB * NQ / ROWS_PER_BLK);  // 512 blocks = 2/CU, one dispatch round
    dim3 block(NK);                     // 256 threads = 4 waves
    relfeat_mfma_kernel<<<grid, block, 0, stream>>>(q, k, W1, b1, W2, b2, out);
}